// Round 7
// baseline (325.298 us; speedup 1.0000x reference)
//
#include <hip/hip_runtime.h>
#include <stdint.h>

using f32x4   = __attribute__((ext_vector_type(4))) float;
using short8  = __attribute__((ext_vector_type(8))) short;
using float2v = __attribute__((ext_vector_type(2))) float;
using uint4v  = __attribute__((ext_vector_type(4))) unsigned int;

#define NCOL 11008
#define KDIM 4096
#define KSPLIT 8      // 8 ksegs x 512 k each
#define PHASES 16     // 512 k / 32 k-rows per stage tile
#define TILE_B 32768  // stage tile: 32 k-rows x 256 cols fp32 = 32KB

#define AS1 __attribute__((address_space(1)))
#define AS3 __attribute__((address_space(3)))

__device__ __forceinline__ unsigned pk_bf16(float a, float b) {
  unsigned ua = __float_as_uint(a); ua += 0x7fffu + ((ua >> 16) & 1u);  // RNE
  unsigned ub = __float_as_uint(b); ub += 0x7fffu + ((ub >> 16) & 1u);
  return (ua >> 16) | (ub & 0xffff0000u);
}

// ---- kernel 1: mask (fp64-exact; verified green) + write mask-zeroed bf16
//      copy of x into ws. grid (8 rb, 8 kgrp), 256 thr. UNCHANGED.
__global__ __launch_bounds__(256) void mask_convert_kernel(
    const float* __restrict__ x, unsigned* __restrict__ xbf) {
  const int rb = blockIdx.x;
  const int g  = blockIdx.y;
  const int t  = threadIdx.x;
  __shared__ double part[256];
  __shared__ unsigned sh_bits;

  const float* base = x + (size_t)rb * 16 * KDIM + g * 512 + t * 2;
  double s = 0.0;
#pragma unroll
  for (int r = 0; r < 16; ++r) {
    float2v a = *(const float2v*)(base + (size_t)r * KDIM);
    s += (double)fabsf(a[0]) + (double)fabsf(a[1]);
  }
  part[t] = s;
  __syncthreads();
  if (t < 8) {                        // t = kb-local (8 kbs per 512-col group)
    double acc = 0.0;
#pragma unroll
    for (int u = 0; u < 32; ++u) acc += part[t * 32 + u];
    bool on = (acc * (1.0 / 1024.0)) > (double)0.8f;
    unsigned long long bal = __ballot(on);
    if (t == 0) sh_bits = (unsigned)(bal & 0xffu);
  }
  __syncthreads();
  const unsigned keep = (sh_bits >> (t >> 5)) & 1u;

  unsigned* dst = xbf + (size_t)rb * 16 * (KDIM / 2) + g * 256 + t;
#pragma unroll
  for (int r = 0; r < 16; ++r) {      // reload (L1-hot) + pack/zero + store
    float2v a = *(const float2v*)(base + (size_t)r * KDIM);
    dst[(size_t)r * (KDIM / 2)] = keep ? pk_bf16(a[0], a[1]) : 0u;
  }
}

// ---- kernel 1b: out[r][n] = bias[n] so gemm ksegs can atomically accumulate
// order-free. grid (43, 128): 11008 = 43*256 cols, 128 rows.
__global__ __launch_bounds__(256) void bias_init_kernel(
    const float* __restrict__ bias, float* __restrict__ out) {
  const int n = blockIdx.x * 256 + threadIdx.x;
  out[(size_t)blockIdx.y * NCOL + n] = bias[n];
}

// ---- kernel 2: dense GEMM on masked bf16 x. grid (43, KSPLIT=8), 512 thr
// (8 waves = 2 m-groups x 4 n-groups; each wave owns 64 rows x 64 cols).
// M=128 x N=256 per block. THE R6 POST-MORTEM: five execution-structure
// variants (ILP depth, counted vmcnt, ksplit TLP, gl_lds) all pinned at
// gemm ~103-108 us with HBM 0.94 TB/s — the invariant was the ADDRESS
// STREAM: N=32 tiles read W in 128-B granules at 44-KB stride (~random
// 128-B requests -> ~1/4 DRAM efficiency). N=256 makes every staging
// wave-instr a CONTIGUOUS 1-KB burst (64 lanes x 16 B), the m13-verified
// granule for ~6.3 TB/s. W still read exactly once chip-wide.
// Stage tile = 32 k-rows x 256 cols fp32 (32 KB, dbuf 64 KB -> 2 blk/CU,
// 16 waves/CU). gl_lds width=16, linear LDS (lane order matches HW rule).
// fp32->bf16 at fragment build (validated in R6). Atomic kseg accumulate.
__global__ __launch_bounds__(512, 4) void gemm_kernel(
    const unsigned* __restrict__ xbf, const float* __restrict__ w,
    float* __restrict__ out) {

  __shared__ __align__(16) uint8_t lds[2 * TILE_B];

  const int tid  = threadIdx.x;
  const int lane = tid & 63;
  const int wv   = tid >> 6;        // 0..7
  const int c    = lane & 15;
  const int q    = lane >> 4;
  const int mg   = wv >> 2;         // 0..1: rows mg*64..+63
  const int ng   = wv & 3;          // 0..3: cols ng*64..+63
  const int n0   = blockIdx.x * 256;
  const int k0b  = blockIdx.y * 512;   // kseg k-base

  f32x4 acc[4][2][2] = {};          // [fm][colgroup g][even/odd]

  // Staging geometry: round r (0..3), wave wv covers tile-row (r*8 + wv):
  //   one gl_lds instr = 64 lanes x 16 B = the row's FULL 1-KB col-chunk,
  //   contiguous in global. LDS dest uniform base buf + r*8192 + wv*1024
  //   (+ lane*16 by HW) = linear [32][1024B] tile.
  const float* gW = w + n0 + lane * 4;

#define STAGE(BUF, K0)                                                      \
  {                                                                         \
    _Pragma("unroll")                                                       \
    for (int r_ = 0; r_ < 4; ++r_) {                                        \
      __builtin_amdgcn_global_load_lds(                                     \
          (const AS1 void*)(gW + (size_t)((K0) + r_ * 8 + wv) * NCOL),      \
          (AS3 void*)((BUF) + r_ * 8192 + wv * 1024), 16, 0, 0);            \
    }                                                                       \
  }

  // A source (bf16 masked x, L2-resident): uint4v idx = row*512 + k/8
  const uint4v* aBase = (const uint4v*)xbf;

  auto compute = [&](const uint8_t* buf, int k0) {
    union { uint4v u; short8 v; } a[4];
#pragma unroll
    for (int fm = 0; fm < 4; ++fm)
      a[fm].u = aBase[(size_t)(mg * 64 + fm * 16 + c) * 512 + (k0 >> 3) + q];

#pragma unroll
    for (int g = 0; g < 2; ++g) {
      // wave's cols: n0 + ng*64 + g*32 + {2c, 2c+1}; tile row k (0..31) at
      // byte k*1024. Lane reads float2 (cols 2c,2c+1) for k = q*8 + 2p(+1).
      const uint8_t* wb = buf + ng * 256 + g * 128 + c * 8;
      union { short8 v; unsigned u[4]; } be, bo;
#pragma unroll
      for (int p = 0; p < 4; ++p) {
        float2v f0 = *(const float2v*)(wb + (size_t)(q * 8 + 2 * p) * 1024);
        float2v f1 = *(const float2v*)(wb + (size_t)(q * 8 + 2 * p + 1) * 1024);
        be.u[p] = pk_bf16(f0[0], f1[0]);   // col 2c,  k-pair
        bo.u[p] = pk_bf16(f0[1], f1[1]);   // col 2c+1
      }
#pragma unroll
      for (int fm = 0; fm < 4; ++fm) {
        acc[fm][g][0] = __builtin_amdgcn_mfma_f32_16x16x32_bf16(a[fm].v, be.v, acc[fm][g][0], 0, 0, 0);
        acc[fm][g][1] = __builtin_amdgcn_mfma_f32_16x16x32_bf16(a[fm].v, bo.v, acc[fm][g][1], 0, 0, 0);
      }
    }
  };

  uint8_t* const buf0 = lds;
  uint8_t* const buf1 = lds + TILE_B;

  STAGE(buf0, k0b);
  __syncthreads();                 // retires stage(0)

  int p = 0;
  for (int ph = 0; ph < PHASES; ++ph) {
    uint8_t* cur = p ? buf1 : buf0;
    uint8_t* nxt = p ? buf0 : buf1;
    if (ph + 1 < PHASES) STAGE(nxt, k0b + (ph + 1) * 32);  // in flight during compute
    compute(cur, k0b + ph * 32);
    __syncthreads();               // retires stage(ph+1); guards cur reuse
    p ^= 1;
  }
#undef STAGE

  // epilogue: D row = mg*64 + fm*16 + q*4 + pp, cols n0 + ng*64 + g*32 +
  // {2c,2c+1}; native fp32 atomic add (relaxed, agent scope). 8 ksegs per
  // address, lane-disjoint -> negligible contention.
  const int colE = n0 + ng * 64 + 2 * c;
#pragma unroll
  for (int fm = 0; fm < 4; ++fm) {
#pragma unroll
    for (int g = 0; g < 2; ++g) {
#pragma unroll
      for (int pp = 0; pp < 4; ++pp) {
        const int row = mg * 64 + fm * 16 + q * 4 + pp;
        float* pd = out + (size_t)row * NCOL + colE + g * 32;
        __hip_atomic_fetch_add(pd,     acc[fm][g][0][pp], __ATOMIC_RELAXED,
                               __HIP_MEMORY_SCOPE_AGENT);
        __hip_atomic_fetch_add(pd + 1, acc[fm][g][1][pp], __ATOMIC_RELAXED,
                               __HIP_MEMORY_SCOPE_AGENT);
      }
    }
  }
}

extern "C" void kernel_launch(void* const* d_in, const int* in_sizes, int n_in,
                              void* d_out, int out_size, void* d_ws, size_t ws_size,
                              hipStream_t stream) {
  const float* x    = (const float*)d_in[0];
  const float* w    = (const float*)d_in[1];
  const float* bias = (const float*)d_in[2];
  float* out        = (float*)d_out;
  unsigned* xbf     = (unsigned*)d_ws;    // 128 x 4096 bf16 (1 MiB)

  hipLaunchKernelGGL(mask_convert_kernel, dim3(8, 8), dim3(256), 0, stream, x, xbf);
  hipLaunchKernelGGL(bias_init_kernel, dim3(43, 128), dim3(256), 0, stream, bias, out);
  hipLaunchKernelGGL(gemm_kernel, dim3(43, KSPLIT), dim3(512), 0, stream,
                     xbf, w, out);
}